// Round 10
// baseline (291.964 us; speedup 1.0000x reference)
//
#include <hip/hip_runtime.h>
#include <math.h>

// Side-window filter, 3 iterations fused, FP32, bit-exact vs the np reference
// (verified absmax==0.0): each directional conv is a sequential fp32 FMA chain
// over taps in row-major (ky,kx) order, weights fp32(1/15), fp32(1/9),
// fp32(fp32(1/9)/9). Zero-padded taps are exact no-ops; chain heads are muls
// (== fmaf onto +0, verified bit-exact in round 4). Intermediates fp32;
// out-of-image intermediate pixels zeroed (next iteration zero-pads).
//
// Round 16: I-cache test. Elimination table after 9 rounds: occupancy (R1/R9,
// both directions), op count (R5/R7), LDS traffic (R8: -35% ds_reads -> flat),
// register budget (R6/R8), wave imbalance (R7). True issue util ~47%; ~45 us
// of stall unexplained. Last counter-invisible suspect: instruction fetch —
// the fully-unrolled body is ~21-25 KB straight-line (3 step instantiations),
// vs 32 KB I$ shared per CU-cluster with 5-6 resident blocks at different
// pipeline phases. Fix: emit the piece body ONCE as a __noinline__ worker
// (runtime pitch/stride/len/mask-mode); the three steps become thin mapping +
// call. Code ~21 KB -> ~9 KB. Math byte-identical. Base config = round 8
// ((256,5), rolling window, clean 55.3 MB writes, 115.3 us) — note (256,6)
// with this body triggers a +37 MB L2 write-pressure artifact (R9: 123 us).
//
// Round 14 (kept): rolling tap-row window. Round 13 (kept): balanced piece
// mapping (exactly 256 pieces of 2-3 same-parity rows per step).
// Round 11 (kept): exact-sharing. Four BITWISE identities:
//   L[x,y] == R[x-2,y]   (w15, 5 rows x 3 cols)
//   U[x,y] == D[x,y-2]   (w15, 3 rows x 5 cols)
//   NW[x,y]== SW[x,y-2]  (w9,  3x3, cols x-2..x)
//   NE[x,y]== SE[x,y-2]  (w81, same support as NW/SW — the reference bug)
//
// Direction supports (with the reference's normalization bug):
//   d0 L  = rows[-2..2] x cols[-2..0] * (1/15)
//   d1 R  = rows[-2..2] x cols[0..2]  * (1/15)
//   d2 U  = rows[-2..0] x cols[-2..2] * (1/15)
//   d3 D  = rows[0..2]  x cols[-2..2] * (1/15)
//   d4 NW = rows[-2..0] x cols[-2..0] * (1/9)
//   d5 NE = NW support * (1/81)
//   d6 SW = rows[0..2]  x cols[-2..0] * (1/9)
//   d7 SE = SW support * (1/81)

typedef float f4v __attribute__((ext_vector_type(4)));
typedef float f2v __attribute__((ext_vector_type(2), aligned(8)));

struct Row8 { f4v lo, hi; };

__device__ __forceinline__ void ldrow(Row8& t, const float* p) {
    t.lo = *(const f4v*)p;          // 16B-aligned
    t.hi = *(const f4v*)(p + 4);
}

// Process one tap row (compile-time r = 0..4) for a 4-px output row.
// Chain order per accumulator: tap rows ascending, cols ascending within row
// — the verified bit-exact chain. Do not reorder within a chain.
template<int r, bool FULL>
__device__ __forceinline__ void tap_row(const Row8& t,
        float* Rv, float* Dv, float* SWv, float* SEv,
        float* Uv, float* NWv, float* NEv, float* ctr) {
    const float w15 = 1.0f / 15.0f;
    const float w9  = 1.0f / 9.0f;
    const float w81 = (1.0f / 9.0f) / 9.0f;

    float w[8] = {t.lo.x, t.lo.y, t.lo.z, t.lo.w,
                  t.hi.x, t.hi.y, t.hi.z, t.hi.w};

    // R chains at 6 positions; w[q] = tap col x0-2+q
    #pragma unroll
    for (int q = 0; q < 6; q++) {
        float a = (r == 0) ? (w15 * w[q]) : fmaf(w15, w[q], Rv[q]);
        a = fmaf(w15, w[q + 1], a);
        a = fmaf(w15, w[q + 2], a);
        Rv[q] = a;
    }

    #pragma unroll
    for (int j = 0; j < 4; j++) {
        if (FULL && r < 3) {           // U, NW, NE (tap rows y-2..y)
            float u = (r == 0) ? (w15 * w[j]) : fmaf(w15, w[j], Uv[j]);
            u = fmaf(w15, w[j + 1], u);
            u = fmaf(w15, w[j + 2], u);
            u = fmaf(w15, w[j + 3], u);
            u = fmaf(w15, w[j + 4], u);
            Uv[j] = u;
            float nw = (r == 0) ? (w9 * w[j]) : fmaf(w9, w[j], NWv[j]);
            nw = fmaf(w9, w[j + 1], nw);
            nw = fmaf(w9, w[j + 2], nw);
            NWv[j] = nw;
            float ne = (r == 0) ? (w81 * w[j]) : fmaf(w81, w[j], NEv[j]);
            ne = fmaf(w81, w[j + 1], ne);
            ne = fmaf(w81, w[j + 2], ne);
            NEv[j] = ne;
        }
        if (r >= 2) {                  // D, SW, SE (tap rows y..y+2)
            float d = (r == 2) ? (w15 * w[j]) : fmaf(w15, w[j], Dv[j]);
            d = fmaf(w15, w[j + 1], d);
            d = fmaf(w15, w[j + 2], d);
            d = fmaf(w15, w[j + 3], d);
            d = fmaf(w15, w[j + 4], d);
            Dv[j] = d;
            float sw = (r == 2) ? (w9 * w[j]) : fmaf(w9, w[j], SWv[j]);
            sw = fmaf(w9, w[j + 1], sw);
            sw = fmaf(w9, w[j + 2], sw);
            SWv[j] = sw;
            float se = (r == 2) ? (w81 * w[j]) : fmaf(w81, w[j], SEv[j]);
            se = fmaf(w81, w[j + 1], se);
            se = fmaf(w81, w[j + 2], se);
            SEv[j] = se;
            if (r == 2) ctr[j] = w[j + 2];
        }
    }
}

// One output row from 5 resident tap rows.
template<bool FULL>
__device__ __forceinline__ void swf_row_regs(
        const Row8& t0, const Row8& t1, const Row8& t2,
        const Row8& t3, const Row8& t4,
        float* Rv, float* Dv, float* SWv, float* SEv,
        float* Uv, float* NWv, float* NEv, float* ctr) {
    tap_row<0, FULL>(t0, Rv, Dv, SWv, SEv, Uv, NWv, NEv, ctr);
    tap_row<1, FULL>(t1, Rv, Dv, SWv, SEv, Uv, NWv, NEv, ctr);
    tap_row<2, FULL>(t2, Rv, Dv, SWv, SEv, Uv, NWv, NEv, ctr);
    tap_row<3, FULL>(t3, Rv, Dv, SWv, SEv, Uv, NWv, NEv, ctr);
    tap_row<4, FULL>(t4, Rv, Dv, SWv, SEv, Uv, NWv, NEv, ctr);
}

// argmin tournament + store for one 4-px row, runtime mask mode.
// e-order (L,R,U,D,NW,NE,SW,SE) and strict-< tree identical to the verified
// kernel (lowest index on ties; |x| folds into VOP3 abs modifiers).
__device__ __forceinline__ void emit_rt(const float* Rv,
        const float* Ua, const float* NWa, const float* NEa,
        const float* Dn, const float* SWn, const float* SEn, const float* ctr,
        float* __restrict__ p, int mode, int gy, int gx) {
    f4v R;
    #pragma unroll
    for (int j = 0; j < 4; j++) {
        const float c  = ctr[j];
        const float e0 = Rv[j]     - c;   // L  == R[x-2] (same row)
        const float e1 = Rv[j + 2] - c;   // R
        const float e2 = Ua[j]     - c;   // U  (fresh or D[y-2])
        const float e3 = Dn[j]     - c;   // D
        const float e4 = NWa[j]    - c;   // NW (fresh or SW[y-2])
        const float e5 = NEa[j]    - c;   // NE (fresh or SE[y-2])
        const float e6 = SWn[j]    - c;   // SW
        const float e7 = SEn[j]    - c;   // SE
        float m01 = (fabsf(e1) < fabsf(e0)) ? e1 : e0;
        float m23 = (fabsf(e3) < fabsf(e2)) ? e3 : e2;
        float m45 = (fabsf(e5) < fabsf(e4)) ? e5 : e4;
        float m67 = (fabsf(e7) < fabsf(e6)) ? e7 : e6;
        float mA  = (fabsf(m23) < fabsf(m01)) ? m23 : m01;
        float mB  = (fabsf(m67) < fabsf(m45)) ? m67 : m45;
        float bd  = (fabsf(mB)  < fabsf(mA))  ? mB  : mA;
        const float res = c + bd;
        if (j == 0) R.x = res; else if (j == 1) R.y = res;
        else if (j == 2) R.z = res; else R.w = res;
    }
    if (mode) {
        // zero outside the image: next iteration zero-pads at the boundary
        const bool rowin = ((unsigned)gy < 768u);
        R.x = (rowin && (unsigned)(gx + 0) < 768u) ? R.x : 0.0f;
        R.y = (rowin && (unsigned)(gx + 1) < 768u) ? R.y : 0.0f;
        R.z = (rowin && (unsigned)(gx + 2) < 768u) ? R.z : 0.0f;
        R.w = (rowin && (unsigned)(gx + 3) < 768u) ? R.w : 0.0f;
    }
    *(f4v*)p = R;
}

// The piece body, emitted ONCE (I$ footprint). rp = X + y*PW + x0 in LDS;
// sp = store ptr for row y (stride sstride floats, rows advance by 2);
// mode 0 = plain store (interior or last iter), 1 = boundary-masked;
// gy/gx = global coords of (row y, col x0) for masking. len = 2 or 3 rows.
// First row FULL (fresh U/NW/NE, bitwise == ring values); later rows reuse
// the previous row's D/SW/SE via the exact identities.
__device__ __noinline__ void piece_worker(const float* __restrict__ rp, int PW,
                                          int len, float* __restrict__ sp,
                                          int sstride, int mode, int gy, int gx) {
    // rolling tap window: rows y..y+6 (t5,t6 prefetched ahead of row-y math)
    Row8 t0, t1, t2, t3, t4, t5, t6;
    ldrow(t0, rp);
    ldrow(t1, rp + PW);
    ldrow(t2, rp + 2 * PW);
    ldrow(t3, rp + 3 * PW);
    ldrow(t4, rp + 4 * PW);
    ldrow(t5, rp + 5 * PW);
    ldrow(t6, rp + 6 * PW);

    float Rv[6], D0[4], S0[4], E0[4], U0[4], N0[4], M0[4], ctr[4];
    // row y: full (fresh U/NW/NE)
    swf_row_regs<true >(t0, t1, t2, t3, t4, Rv, D0, S0, E0, U0, N0, M0, ctr);
    emit_rt(Rv, U0, N0, M0, D0, S0, E0, ctr, sp, mode, gy, gx);
    // row y+2: taps t2..t6 (3/5 resident); U/NW/NE = row y's D/SW/SE
    float D1[4], S1[4], E1[4];
    swf_row_regs<false>(t2, t3, t4, t5, t6, Rv, D1, S1, E1, U0, N0, M0, ctr);
    emit_rt(Rv, D0, S0, E0, D1, S1, E1, ctr, sp + 2 * sstride, mode, gy + 2, gx);
    // row y+4 (len-3 pieces): taps t4,t5,t6 + reloaded rows y+7,y+8
    if (len == 3) {
        ldrow(t0, rp + 7 * PW);
        ldrow(t1, rp + 8 * PW);
        swf_row_regs<false>(t4, t5, t6, t0, t1, Rv, D0, S0, E0, U0, N0, M0, ctr);
        emit_rt(Rv, D1, S1, E1, D0, S0, E0, ctr, sp + 4 * sstride, mode, gy + 4, gx);
    }
}

// One SWF iteration: compile-time piece mapping + one worker call.
// X: (H2+4) x (W2+4) LDS tile (pitch W2+4, zero-pad). A "run" = (strip,
// parity); each run is cut into pieces of 2-3 same-parity consecutive rows;
// exactly 256 pieces per step (all threads busy, waves length-pure except
// one boundary wave; consecutive lanes read consecutive strips).
template<int H2, int W2, bool LAST>
__device__ __forceinline__ void stepv(const float* __restrict__ X,
                                      float* __restrict__ Y,
                                      float* __restrict__ outp,
                                      int gy0, int gx0, int tid) {
    constexpr int PW     = W2 + 4;
    constexpr int STRIPS = W2 / 4;                    // 18 / 17 / 16
    static_assert(H2 == 40 || H2 == 36 || H2 == 32, "piece tables");

    const bool interior = (gy0 >= 0) && (gx0 >= 0) &&
                          (gy0 + H2 <= 768) && (gx0 + W2 <= 768);

    int run, start, len;                  // start in parity-row units
    if constexpr (H2 == 40) {
        // 36 runs x 20 parity-rows = 720 rows, 256 pieces (48 len2, 208 len3).
        if (tid < 16)      { run = tid & 3;              start = 2 * (tid >> 2);        len = 2; }
        else if (tid < 48) { run = 4 + ((tid - 16) & 31); start = 0;                    len = 2; }
        else if (tid < 64) { int u = tid - 48; run = u & 3;        start = 8 + 3 * (u >> 2); len = 3; }
        else               { int u = tid - 64; run = 4 + (u & 31); start = 2 + 3 * (u >> 5); len = 3; }
    } else if constexpr (H2 == 36) {
        // 34 runs x 18 = 612 rows, 256 pieces (156 len2, 100 len3).
        if (tid < 108)      { run = tid % 18;                      start = 2 * (tid / 18);     len = 2; }
        else if (tid < 156) { int u = tid - 108; run = 18 + (u & 15); start = 2 * (u >> 4);    len = 2; }
        else if (tid < 192) { int u = tid - 156; run = u % 18;        start = 12 + 3 * (u / 18); len = 3; }
        else                { int u = tid - 192; run = 18 + (u & 15); start = 6 + 3 * (u >> 4);  len = 3; }
    } else {
        // 32 runs x 16 = 512 rows, 256 pieces, all len2.
        run = tid & 31; start = 2 * (tid >> 5); len = 2;
    }

    const int par   = (run >= STRIPS) ? 1 : 0;
    const int strip = run - par * STRIPS;
    const int x0    = strip * 4;
    const int y     = par + 2 * start;

    float* sp;
    int sstride, mode;
    if (LAST) {
        sp = outp + y * 768 + x0; sstride = 768; mode = 0;
    } else {
        sp = Y + y * W2 + x0; sstride = W2; mode = interior ? 0 : 1;
    }
    piece_worker(X + y * PW + x0, PW, len, sp, sstride, mode,
                 gy0 + y, gx0 + x0);
    __syncthreads();
}

// LDS: A = 44x76 fp32 (iter1 input; reused as iter2 output 36x68) = 13376 B,
//      B = 40x72 fp32 (iter1 output = iter2 input) = 11520 B. Total 24896 B.
// launch_bounds(256,5) = round 8's measured-clean config (6 blocks/CU with
// this body triggers a +37 MB L2 write-pressure artifact and runs slower).
__global__ __launch_bounds__(256, 5) void swf_fused(const float* __restrict__ in,
                                                    float* __restrict__ out) {
    __shared__ __align__(16) float A[44 * 76];
    __shared__ __align__(16) float B[40 * 72];

    const int tid = threadIdx.x;
    const int tx0 = blockIdx.x * 64;
    const int ty0 = blockIdx.y * 32;
    const long long base = (long long)blockIdx.z * (768 * 768);
    const float* inp = in + base;

    // load tile rows ty0-6..ty0+37, cols tx0-6..tx0+69, zero-padded.
    // float2 granularity: global col tx0-6 is even -> 8B aligned.
    for (int i = tid; i < 44 * 38; i += 256) {
        const int ly  = i / 38;
        const int lx2 = i - ly * 38;
        const int gy  = ty0 + ly - 6;
        const int gx  = tx0 + lx2 * 2 - 6;
        f2v v = {0.0f, 0.0f};
        if ((unsigned)gy < 768u) {
            const float* g = inp + gy * 768 + gx;
            if ((unsigned)gx < 767u) {            // both lanes inside
                v = *(const f2v*)g;
            } else {                               // x-edge: per-lane
                if ((unsigned)gx < 768u)       v.x = g[0];
                if ((unsigned)(gx + 1) < 768u) v.y = g[1];
            }
        }
        *(f2v*)(A + ly * 76 + lx2 * 2) = v;
    }
    __syncthreads();

    stepv<40, 72, false>(A, B, nullptr, ty0 - 4, tx0 - 4, tid);  // iter1: A->B
    stepv<36, 68, false>(B, A, nullptr, ty0 - 2, tx0 - 2, tid);  // iter2: B->A
    stepv<32, 64, true >(A, nullptr,                              // iter3: A->out
                         out + base + (long long)ty0 * 768 + tx0, ty0, tx0, tid);
}

extern "C" void kernel_launch(void* const* d_in, const int* in_sizes, int n_in,
                              void* d_out, int out_size, void* d_ws, size_t ws_size,
                              hipStream_t stream) {
    const float* x = (const float*)d_in[0];
    float* out = (float*)d_out;

    dim3 grid(768 / 64, 768 / 32, 24);   // 12 x 24 x 24 = 6912 blocks
    dim3 block(256);
    swf_fused<<<grid, block, 0, stream>>>(x, out);
}

// Round 11
// 186.015 us; speedup vs baseline: 1.5696x; 1.5696x over previous
//
#include <hip/hip_runtime.h>
#include <math.h>

// Side-window filter, 3 iterations fused, FP32, bit-exact vs the np reference
// (verified absmax==0.0): each directional conv is a sequential fp32 FMA chain
// over taps in row-major (ky,kx) order, weights fp32(1/15), fp32(1/9),
// fp32(fp32(1/9)/9). Zero-padded taps are exact no-ops; chain heads are muls
// (== fmaf onto +0, verified bit-exact in round 4). Intermediates fp32;
// out-of-image intermediate pixels zeroed (next iteration zero-pads).
//
// Round 17: REVERT to round 8 (best measured: 115.3 us/dispatch, 183.4 us
// bench). Round 10's __noinline__ I$ test self-destructed: the call boundary
// forced ~90 live floats through the ABI -> scratch spill (WRITE_SIZE 55->664
// MB, dur 220 us); the I$ hypothesis is untestable without the spill artifact.
// Elimination table (10 rounds): occupancy both directions (6 blk/CU triggers
// a +37 MB L2-write artifact, 5 blk optimal), structural op count (-30%
// shipped via exact sharing), LDS traffic (-35% reads -> flat, not binding),
// register budget (compiler sinks loads; VGPR never limits), wave imbalance
// (<=6%), dispatch splitting (loses to inter-dispatch gaps). True issue
// utilization ~47%; residual stall is I-fetch/barrier-structural.
//
// Round 14 (kept): rolling tap-row window (rows y,y+2 share t2..t4; row y+4
// reuses t4..t6 + 2 reloads). Round 13 (kept): balanced piece mapping
// (exactly 256 pieces of 2-3 same-parity rows per step, len-2-first).
// Round 11 (kept): exact-sharing. Four BITWISE identities:
//   L[x,y] == R[x-2,y]   (w15, 5 rows x 3 cols)
//   U[x,y] == D[x,y-2]   (w15, 3 rows x 5 cols)
//   NW[x,y]== SW[x,y-2]  (w9,  3x3, cols x-2..x)
//   NE[x,y]== SE[x,y-2]  (w81, same support as NW/SW — the reference bug)
//
// Direction supports (with the reference's normalization bug):
//   d0 L  = rows[-2..2] x cols[-2..0] * (1/15)
//   d1 R  = rows[-2..2] x cols[0..2]  * (1/15)
//   d2 U  = rows[-2..0] x cols[-2..2] * (1/15)
//   d3 D  = rows[0..2]  x cols[-2..2] * (1/15)
//   d4 NW = rows[-2..0] x cols[-2..0] * (1/9)
//   d5 NE = NW support * (1/81)
//   d6 SW = rows[0..2]  x cols[-2..0] * (1/9)
//   d7 SE = SW support * (1/81)

typedef float f4v __attribute__((ext_vector_type(4)));
typedef float f2v __attribute__((ext_vector_type(2), aligned(8)));

struct Row8 { f4v lo, hi; };

__device__ __forceinline__ void ldrow(Row8& t, const float* p) {
    t.lo = *(const f4v*)p;          // 16B-aligned
    t.hi = *(const f4v*)(p + 4);
}

// Process one tap row (compile-time r = 0..4) for a 4-px output row.
// Chain order per accumulator: tap rows ascending, cols ascending within row
// — the verified bit-exact chain. Do not reorder within a chain.
template<int r, bool FULL>
__device__ __forceinline__ void tap_row(const Row8& t,
        float* Rv, float* Dv, float* SWv, float* SEv,
        float* Uv, float* NWv, float* NEv, float* ctr) {
    const float w15 = 1.0f / 15.0f;
    const float w9  = 1.0f / 9.0f;
    const float w81 = (1.0f / 9.0f) / 9.0f;

    float w[8] = {t.lo.x, t.lo.y, t.lo.z, t.lo.w,
                  t.hi.x, t.hi.y, t.hi.z, t.hi.w};

    // R chains at 6 positions; w[q] = tap col x0-2+q
    #pragma unroll
    for (int q = 0; q < 6; q++) {
        float a = (r == 0) ? (w15 * w[q]) : fmaf(w15, w[q], Rv[q]);
        a = fmaf(w15, w[q + 1], a);
        a = fmaf(w15, w[q + 2], a);
        Rv[q] = a;
    }

    #pragma unroll
    for (int j = 0; j < 4; j++) {
        if (FULL && r < 3) {           // U, NW, NE (tap rows y-2..y)
            float u = (r == 0) ? (w15 * w[j]) : fmaf(w15, w[j], Uv[j]);
            u = fmaf(w15, w[j + 1], u);
            u = fmaf(w15, w[j + 2], u);
            u = fmaf(w15, w[j + 3], u);
            u = fmaf(w15, w[j + 4], u);
            Uv[j] = u;
            float nw = (r == 0) ? (w9 * w[j]) : fmaf(w9, w[j], NWv[j]);
            nw = fmaf(w9, w[j + 1], nw);
            nw = fmaf(w9, w[j + 2], nw);
            NWv[j] = nw;
            float ne = (r == 0) ? (w81 * w[j]) : fmaf(w81, w[j], NEv[j]);
            ne = fmaf(w81, w[j + 1], ne);
            ne = fmaf(w81, w[j + 2], ne);
            NEv[j] = ne;
        }
        if (r >= 2) {                  // D, SW, SE (tap rows y..y+2)
            float d = (r == 2) ? (w15 * w[j]) : fmaf(w15, w[j], Dv[j]);
            d = fmaf(w15, w[j + 1], d);
            d = fmaf(w15, w[j + 2], d);
            d = fmaf(w15, w[j + 3], d);
            d = fmaf(w15, w[j + 4], d);
            Dv[j] = d;
            float sw = (r == 2) ? (w9 * w[j]) : fmaf(w9, w[j], SWv[j]);
            sw = fmaf(w9, w[j + 1], sw);
            sw = fmaf(w9, w[j + 2], sw);
            SWv[j] = sw;
            float se = (r == 2) ? (w81 * w[j]) : fmaf(w81, w[j], SEv[j]);
            se = fmaf(w81, w[j + 1], se);
            se = fmaf(w81, w[j + 2], se);
            SEv[j] = se;
            if (r == 2) ctr[j] = w[j + 2];
        }
    }
}

// One output row from 5 resident tap rows.
template<bool FULL>
__device__ __forceinline__ void swf_row_regs(
        const Row8& t0, const Row8& t1, const Row8& t2,
        const Row8& t3, const Row8& t4,
        float* Rv, float* Dv, float* SWv, float* SEv,
        float* Uv, float* NWv, float* NEv, float* ctr) {
    tap_row<0, FULL>(t0, Rv, Dv, SWv, SEv, Uv, NWv, NEv, ctr);
    tap_row<1, FULL>(t1, Rv, Dv, SWv, SEv, Uv, NWv, NEv, ctr);
    tap_row<2, FULL>(t2, Rv, Dv, SWv, SEv, Uv, NWv, NEv, ctr);
    tap_row<3, FULL>(t3, Rv, Dv, SWv, SEv, Uv, NWv, NEv, ctr);
    tap_row<4, FULL>(t4, Rv, Dv, SWv, SEv, Uv, NWv, NEv, ctr);
}

// argmin tournament + store for one 4-px row. e-order (L,R,U,D,NW,NE,SW,SE)
// and strict-< tree identical to the verified kernel (lowest index on ties).
template<int W2, bool LAST>
__device__ __forceinline__ void emit_store(const float* Rv,
        const float* Ua, const float* NWa, const float* NEa,
        const float* Dn, const float* SWn, const float* SEn, const float* ctr,
        float* __restrict__ Y, float* __restrict__ outp,
        int y, int x0, int gy0, int gx0, bool interior) {
    f4v R;
    #pragma unroll
    for (int j = 0; j < 4; j++) {
        const float c  = ctr[j];
        const float e0 = Rv[j]     - c;   // L  == R[x-2] (same row)
        const float e1 = Rv[j + 2] - c;   // R
        const float e2 = Ua[j]     - c;   // U  (fresh or D[y-2])
        const float e3 = Dn[j]     - c;   // D
        const float e4 = NWa[j]    - c;   // NW (fresh or SW[y-2])
        const float e5 = NEa[j]    - c;   // NE (fresh or SE[y-2])
        const float e6 = SWn[j]    - c;   // SW
        const float e7 = SEn[j]    - c;   // SE
        float m01 = (fabsf(e1) < fabsf(e0)) ? e1 : e0;
        float m23 = (fabsf(e3) < fabsf(e2)) ? e3 : e2;
        float m45 = (fabsf(e5) < fabsf(e4)) ? e5 : e4;
        float m67 = (fabsf(e7) < fabsf(e6)) ? e7 : e6;
        float mA  = (fabsf(m23) < fabsf(m01)) ? m23 : m01;
        float mB  = (fabsf(m67) < fabsf(m45)) ? m67 : m45;
        float bd  = (fabsf(mB)  < fabsf(mA))  ? mB  : mA;
        const float res = c + bd;
        if (j == 0) R.x = res; else if (j == 1) R.y = res;
        else if (j == 2) R.z = res; else R.w = res;
    }
    if (LAST) {
        *(f4v*)(outp + y * 768 + x0) = R;
    } else if (interior) {
        *(f4v*)(Y + y * W2 + x0) = R;
    } else {
        // zero outside the image: next iteration zero-pads at the boundary
        const bool rowin = ((unsigned)(gy0 + y) < 768u);
        R.x = (rowin && (unsigned)(gx0 + x0 + 0) < 768u) ? R.x : 0.0f;
        R.y = (rowin && (unsigned)(gx0 + x0 + 1) < 768u) ? R.y : 0.0f;
        R.z = (rowin && (unsigned)(gx0 + x0 + 2) < 768u) ? R.z : 0.0f;
        R.w = (rowin && (unsigned)(gx0 + x0 + 3) < 768u) ? R.w : 0.0f;
        *(f4v*)(Y + y * W2 + x0) = R;
    }
}

// One SWF iteration, balanced piece mapping + rolling tap window.
// X: (H2+4) x (W2+4) LDS tile (pitch W2+4, zero-pad). A "run" = (strip,
// parity); each run is cut into pieces of 2-3 same-parity consecutive rows;
// exactly 256 pieces per step. First row of a piece is FULL (fresh U/NW/NE,
// bitwise == ring values); rows 2-3 reuse the previous row's D/SW/SE.
template<int H2, int W2, bool LAST>
__device__ __forceinline__ void stepv(const float* __restrict__ X,
                                      float* __restrict__ Y,
                                      float* __restrict__ outp,
                                      int gy0, int gx0, int tid) {
    constexpr int PW     = W2 + 4;
    constexpr int STRIPS = W2 / 4;                    // 18 / 17 / 16
    static_assert(H2 == 40 || H2 == 36 || H2 == 32, "piece tables");

    const bool interior = (gy0 >= 0) && (gx0 >= 0) &&
                          (gy0 + H2 <= 768) && (gx0 + W2 <= 768);

    int run, start, len;                  // start in parity-row units
    if constexpr (H2 == 40) {
        // 36 runs x 20 parity-rows = 720 rows, 256 pieces (48 len2, 208 len3).
        if (tid < 16)      { run = tid & 3;              start = 2 * (tid >> 2);        len = 2; }
        else if (tid < 48) { run = 4 + ((tid - 16) & 31); start = 0;                    len = 2; }
        else if (tid < 64) { int u = tid - 48; run = u & 3;        start = 8 + 3 * (u >> 2); len = 3; }
        else               { int u = tid - 64; run = 4 + (u & 31); start = 2 + 3 * (u >> 5); len = 3; }
    } else if constexpr (H2 == 36) {
        // 34 runs x 18 = 612 rows, 256 pieces (156 len2, 100 len3).
        if (tid < 108)      { run = tid % 18;                      start = 2 * (tid / 18);     len = 2; }
        else if (tid < 156) { int u = tid - 108; run = 18 + (u & 15); start = 2 * (u >> 4);    len = 2; }
        else if (tid < 192) { int u = tid - 156; run = u % 18;        start = 12 + 3 * (u / 18); len = 3; }
        else                { int u = tid - 192; run = 18 + (u & 15); start = 6 + 3 * (u >> 4);  len = 3; }
    } else {
        // 32 runs x 16 = 512 rows, 256 pieces, all len2.
        run = tid & 31; start = 2 * (tid >> 5); len = 2;
    }

    const int par   = (run >= STRIPS) ? 1 : 0;
    const int strip = run - par * STRIPS;
    const int x0    = strip * 4;
    const int y     = par + 2 * start;

    const float* rp = X + y * PW + x0;

    // rolling tap window: rows y..y+6 (t5,t6 prefetched ahead of row-y math)
    Row8 t0, t1, t2, t3, t4, t5, t6;
    ldrow(t0, rp);
    ldrow(t1, rp + PW);
    ldrow(t2, rp + 2 * PW);
    ldrow(t3, rp + 3 * PW);
    ldrow(t4, rp + 4 * PW);
    ldrow(t5, rp + 5 * PW);
    ldrow(t6, rp + 6 * PW);

    float Rv[6], D0[4], S0[4], E0[4], U0[4], N0[4], M0[4], ctr[4];
    // row y: full (fresh U/NW/NE)
    swf_row_regs<true >(t0, t1, t2, t3, t4, Rv, D0, S0, E0, U0, N0, M0, ctr);
    emit_store<W2, LAST>(Rv, U0, N0, M0, D0, S0, E0, ctr,
                         Y, outp, y, x0, gy0, gx0, interior);
    // row y+2: taps t2..t6 (3/5 already resident); U/NW/NE = row y's D/SW/SE
    float D1[4], S1[4], E1[4];
    swf_row_regs<false>(t2, t3, t4, t5, t6, Rv, D1, S1, E1, U0, N0, M0, ctr);
    emit_store<W2, LAST>(Rv, D0, S0, E0, D1, S1, E1, ctr,
                         Y, outp, y + 2, x0, gy0, gx0, interior);
    // row y+4 (len-3 pieces): taps t4,t5,t6 + reloaded t0,t1 (rows y+7,y+8)
    if (len == 3) {
        ldrow(t0, rp + 7 * PW);
        ldrow(t1, rp + 8 * PW);
        swf_row_regs<false>(t4, t5, t6, t0, t1, Rv, D0, S0, E0, U0, N0, M0, ctr);
        emit_store<W2, LAST>(Rv, D1, S1, E1, D0, S0, E0, ctr,
                             Y, outp, y + 4, x0, gy0, gx0, interior);
    }
    __syncthreads();
}

// LDS: A = 44x76 fp32 (iter1 input; reused as iter2 output 36x68) = 13376 B,
//      B = 40x72 fp32 (iter1 output = iter2 input) = 11520 B. Total 24896 B.
// launch_bounds(256,5): round 8's measured-best config. (256,6) with this
// body triggers a +37 MB L2 write-pressure artifact and runs ~7% slower.
__global__ __launch_bounds__(256, 5) void swf_fused(const float* __restrict__ in,
                                                    float* __restrict__ out) {
    __shared__ __align__(16) float A[44 * 76];
    __shared__ __align__(16) float B[40 * 72];

    const int tid = threadIdx.x;
    const int tx0 = blockIdx.x * 64;
    const int ty0 = blockIdx.y * 32;
    const long long base = (long long)blockIdx.z * (768 * 768);
    const float* inp = in + base;

    // load tile rows ty0-6..ty0+37, cols tx0-6..tx0+69, zero-padded.
    // float2 granularity: global col tx0-6 is even -> 8B aligned.
    for (int i = tid; i < 44 * 38; i += 256) {
        const int ly  = i / 38;
        const int lx2 = i - ly * 38;
        const int gy  = ty0 + ly - 6;
        const int gx  = tx0 + lx2 * 2 - 6;
        f2v v = {0.0f, 0.0f};
        if ((unsigned)gy < 768u) {
            const float* g = inp + gy * 768 + gx;
            if ((unsigned)gx < 767u) {            // both lanes inside
                v = *(const f2v*)g;
            } else {                               // x-edge: per-lane
                if ((unsigned)gx < 768u)       v.x = g[0];
                if ((unsigned)(gx + 1) < 768u) v.y = g[1];
            }
        }
        *(f2v*)(A + ly * 76 + lx2 * 2) = v;
    }
    __syncthreads();

    stepv<40, 72, false>(A, B, nullptr, ty0 - 4, tx0 - 4, tid);  // iter1: A->B
    stepv<36, 68, false>(B, A, nullptr, ty0 - 2, tx0 - 2, tid);  // iter2: B->A
    stepv<32, 64, true >(A, nullptr,                              // iter3: A->out
                         out + base + (long long)ty0 * 768 + tx0, ty0, tx0, tid);
}

extern "C" void kernel_launch(void* const* d_in, const int* in_sizes, int n_in,
                              void* d_out, int out_size, void* d_ws, size_t ws_size,
                              hipStream_t stream) {
    const float* x = (const float*)d_in[0];
    float* out = (float*)d_out;

    dim3 grid(768 / 64, 768 / 32, 24);   // 12 x 24 x 24 = 6912 blocks
    dim3 block(256);
    swf_fused<<<grid, block, 0, stream>>>(x, out);
}